// Round 1
// 842.005 us; speedup vs baseline: 1.2443x; 1.2443x over previous
//
#include <hip/hip_runtime.h>
#include <hip/hip_bf16.h>
#include <math.h>

using bf16 = __hip_bfloat16;

#define H_IMG 128
#define W_IMG 128
#define C_IN  200
#define NCLS  16
#define N0    16384
#define N1    4096
#define N2    1024
#define KNB   16
#define EPS   1e-5f
#define SLOPE 0.01f

__device__ __forceinline__ float ldf(const float* p, long i) { return p[i]; }
__device__ __forceinline__ float ldf(const bf16* p, long i) { return __bfloat162float(p[i]); }
__device__ __forceinline__ float leaky(float v) { return v >= 0.f ? v : SLOPE * v; }

__device__ __forceinline__ float4 ld4(const float* p, long i) {
    return *reinterpret_cast<const float4*>(p + i);
}
__device__ __forceinline__ float4 ld4(const bf16* p, long i) {
    const ushort4 u = *reinterpret_cast<const ushort4*>(reinterpret_cast<const unsigned short*>(p) + i);
    float4 r;
    r.x = __uint_as_float((unsigned)u.x << 16);
    r.y = __uint_as_float((unsigned)u.y << 16);
    r.z = __uint_as_float((unsigned)u.z << 16);
    r.w = __uint_as_float((unsigned)u.w << 16);
    return r;
}

// ---------- dtype detector: underlying fp32 read as bf16 stream shows wild exponents ----------
__global__ void detect_kernel(const unsigned short* __restrict__ x, int* __restrict__ flag) {
    int t = threadIdx.x; // 64
    int cnt = 0;
    for (int i = t; i < 4096; i += 64) {
        unsigned short e = (unsigned short)((x[i] >> 7) & 0xFF);
        if (e >= 0xC0) cnt++;
    }
#pragma unroll
    for (int off = 32; off > 0; off >>= 1) cnt += __shfl_xor(cnt, off, 64);
    if (t == 0) *flag = (cnt > 32) ? 1 : 0;
}

// ---------------- BN stats: stage A (coalesced row-major partial sums) ----------------
// part layout: part[c*256 + b] sums, part[65536 + c*256 + b] sumsq
template <typename TX>
__device__ __forceinline__ void bnA_body(const TX* __restrict__ X, int P, int C, float* __restrict__ part) {
    int b = blockIdx.x;   // 256 blocks
    int t = threadIdx.x;  // 256 threads, thread t = channel t
    int rpb = P >> 8;     // P/256 rows per block
    if (t < C) {
        float s = 0.f, s2 = 0.f;
        long base = (long)b * rpb * C + t;
        for (int r = 0; r < rpb; r++) {
            float v = ldf(X, base + (long)r * C);
            s += v; s2 += v * v;
        }
        part[(long)t * 256 + b] = s;
        part[65536 + (long)t * 256 + b] = s2;
    }
}

__global__ __launch_bounds__(256) void bnA_kernel(const void* X, int P, int C, float* part,
                                                  const int* flag, int xraw) {
    if (*flag || !xraw) bnA_body<float>((const float*)X, P, C, part);
    else bnA_body<bf16>((const bf16*)X, P, C, part);
}

// ---------------- BN stats: stage B (reduce 256 partials per channel -> alpha/beta) ----------------
__global__ __launch_bounds__(256) void bnB_kernel(const float* __restrict__ part, int P,
                                                  const void* g, const void* b_,
                                                  float* __restrict__ alpha, float* __restrict__ beta,
                                                  const int* flag) {
    int c = blockIdx.x;
    int t = threadIdx.x;
    __shared__ float rs[256], rq[256];
    rs[t] = part[(long)c * 256 + t];
    rq[t] = part[65536 + (long)c * 256 + t];
    __syncthreads();
    for (int k = 128; k > 0; k >>= 1) {
        if (t < k) { rs[t] += rs[t + k]; rq[t] += rq[t + k]; }
        __syncthreads();
    }
    if (t == 0) {
        float mu = rs[0] / (float)P;
        float var = rq[0] / (float)P - mu * mu;
        float gv = *flag ? ((const float*)g)[c] : __bfloat162float(((const bf16*)g)[c]);
        float bv = *flag ? ((const float*)b_)[c] : __bfloat162float(((const bf16*)b_)[c]);
        float a = rsqrtf(var + EPS) * gv;
        alpha[c] = a;
        beta[c] = bv - mu * a;
    }
}

// ---------------- fold BN into weights ----------------
template <typename TW>
__device__ __forceinline__ void fold_body(const TW* __restrict__ W, const TW* __restrict__ bias,
                                          const float* __restrict__ alpha, const float* __restrict__ beta,
                                          float* __restrict__ Wf, float* __restrict__ Bf,
                                          int Ci, int Co, int omajor, int j) {
    int t = threadIdx.x;
    float acc = 0.f;
    for (int c = t; c < Ci; c += 256) {
        float w = omajor ? ldf(W, (long)j * Ci + c) : ldf(W, (long)c * Co + j);
        Wf[(long)c * Co + j] = w * alpha[c];
        acc += w * beta[c];
    }
    __shared__ float red[256];
    red[t] = acc; __syncthreads();
    for (int k = 128; k > 0; k >>= 1) { if (t < k) red[t] += red[t + k]; __syncthreads(); }
    if (t == 0) Bf[j] = ldf(bias, (long)j) + red[0];
}

__global__ __launch_bounds__(256) void fold_kernel(const void* W, const void* bias,
                                                   const float* alpha, const float* beta,
                                                   float* Wf, float* Bf, int Ci, int Co, int omajor,
                                                   const int* flag) {
    if (*flag) fold_body<float>((const float*)W, (const float*)bias, alpha, beta, Wf, Bf, Ci, Co, omajor, blockIdx.x);
    else fold_body<bf16>((const bf16*)W, (const bf16*)bias, alpha, beta, Wf, Bf, Ci, Co, omajor, blockIdx.x);
}

// fused fold of two weight matrices sharing alpha/beta (GCN wt + wo, both c-major)
__global__ __launch_bounds__(256) void fold2_kernel(const void* W1, const void* b1,
                                                    const void* W2, const void* b2,
                                                    const float* alpha, const float* beta,
                                                    float* Wf1, float* Bf1, float* Wf2, float* Bf2,
                                                    int Ci, int Co1, int Co2, const int* flag) {
    int j = blockIdx.x;
    if (*flag) {
        if (j < Co1) fold_body<float>((const float*)W1, (const float*)b1, alpha, beta, Wf1, Bf1, Ci, Co1, 0, j);
        else fold_body<float>((const float*)W2, (const float*)b2, alpha, beta, Wf2, Bf2, Ci, Co2, 0, j - Co1);
    } else {
        if (j < Co1) fold_body<bf16>((const bf16*)W1, (const bf16*)b1, alpha, beta, Wf1, Bf1, Ci, Co1, 0, j);
        else fold_body<bf16>((const bf16*)W2, (const bf16*)b2, alpha, beta, Wf2, Bf2, Ci, Co2, 0, j - Co1);
    }
}

// ---------------- GEMM: Out[n, j4..j4+3] = act(sum_c In[n,c]*Wf[c,j] + Bf[j]) ----------------
// float4 both sides: 4 outputs/thread, K unrolled by 4 -> 5 VMEM per 16 FMA
template <typename T, int ACT>
__device__ __forceinline__ void gemm4_body(const T* __restrict__ In, const float* __restrict__ Wf,
                                           const float* __restrict__ Bf, float* __restrict__ Out,
                                           int Ci, int Co, int blk) {
    int tid = blk * 256 + threadIdx.x;
    int Coq = Co >> 2;
    int n = tid / Coq;
    int j4 = (tid - n * Coq) << 2;
    const T* in = In + (long)n * Ci;
    const float* wp = Wf + j4;
    float4 acc = *reinterpret_cast<const float4*>(Bf + j4);
    for (int c = 0; c < Ci; c += 4) {
        float4 xv = ld4(in, c);
        float4 w0 = *reinterpret_cast<const float4*>(wp + (long)c * Co);
        float4 w1 = *reinterpret_cast<const float4*>(wp + (long)(c + 1) * Co);
        float4 w2 = *reinterpret_cast<const float4*>(wp + (long)(c + 2) * Co);
        float4 w3 = *reinterpret_cast<const float4*>(wp + (long)(c + 3) * Co);
        acc.x += xv.x * w0.x; acc.y += xv.x * w0.y; acc.z += xv.x * w0.z; acc.w += xv.x * w0.w;
        acc.x += xv.y * w1.x; acc.y += xv.y * w1.y; acc.z += xv.y * w1.z; acc.w += xv.y * w1.w;
        acc.x += xv.z * w2.x; acc.y += xv.z * w2.y; acc.z += xv.z * w2.z; acc.w += xv.z * w2.w;
        acc.x += xv.w * w3.x; acc.y += xv.w * w3.y; acc.z += xv.w * w3.z; acc.w += xv.w * w3.w;
    }
    if (ACT) { acc.x = leaky(acc.x); acc.y = leaky(acc.y); acc.z = leaky(acc.z); acc.w = leaky(acc.w); }
    *reinterpret_cast<float4*>(Out + (long)n * Co + j4) = acc;
}

// head GEMM: In is raw input (dtype dynamic)
__global__ __launch_bounds__(256) void gemm4_dyn_kernel(const void* In, const float* Wf, const float* Bf,
                                                        float* Out, int Ci, int Co, const int* flag) {
    if (*flag) gemm4_body<float, 1>((const float*)In, Wf, Bf, Out, Ci, Co, blockIdx.x);
    else gemm4_body<bf16, 1>((const bf16*)In, Wf, Bf, Out, Ci, Co, blockIdx.x);
}

template <int ACT>
__global__ __launch_bounds__(256) void gemm4_f32_kernel(const float* In, const float* Wf, const float* Bf,
                                                        float* Out, int Ci, int Co) {
    gemm4_body<float, ACT>(In, Wf, Bf, Out, Ci, Co, blockIdx.x);
}

// fused pair of GEMMs sharing the input (GCN theta + out projections)
template <int ACT>
__global__ __launch_bounds__(256) void gemm2_f32_kernel(const float* In,
                                                        const float* W1, const float* B1, float* O1, int Co1,
                                                        const float* W2, const float* B2, float* O2, int Co2,
                                                        int Ci, int nb1) {
    int b = blockIdx.x;
    if (b < nb1) gemm4_body<float, ACT>(In, W1, B1, O1, Ci, Co1, b);
    else gemm4_body<float, ACT>(In, W2, B2, O2, Ci, Co2, b - nb1);
}

// ---------------- depthwise 5x5 SAME + bias + leaky: 4 channels/thread, weights in LDS ----------------
template <typename TW>
__device__ __forceinline__ void dw4_body(const float* __restrict__ In, const TW* __restrict__ dwp,
                                         const TW* __restrict__ dbp, float* __restrict__ Out) {
    __shared__ float wl[25][128];
    __shared__ float bl[128];
    int t = threadIdx.x;
    for (int e = t; e < 25 * 128; e += 256) {
        int o = e / 25, i = e - o * 25;
        wl[i][o] = ldf(dwp, e);   // dwp layout [o][25]; transpose into [tap][channel]
    }
    if (t < 128) bl[t] = ldf(dbp, (long)t);
    __syncthreads();

    int tid = blockIdx.x * 256 + t;    // 16384 pixels * 32 channel-quads
    int o0 = (tid & 31) << 2;
    int p = tid >> 5;
    int h = p >> 7, w = p & 127;
    float4 acc = *reinterpret_cast<const float4*>(&bl[o0]);
#pragma unroll
    for (int dh = -2; dh <= 2; dh++) {
        int hh = h + dh;
        if ((unsigned)hh >= (unsigned)H_IMG) continue;
#pragma unroll
        for (int dv = -2; dv <= 2; dv++) {
            int ww = w + dv;
            if ((unsigned)ww >= (unsigned)W_IMG) continue;
            float4 iv = *reinterpret_cast<const float4*>(&In[(long)(((hh << 7) + ww) << 7) + o0]);
            float4 wv = *reinterpret_cast<const float4*>(&wl[(dh + 2) * 5 + (dv + 2)][o0]);
            acc.x += iv.x * wv.x; acc.y += iv.y * wv.y; acc.z += iv.z * wv.z; acc.w += iv.w * wv.w;
        }
    }
    acc.x = leaky(acc.x); acc.y = leaky(acc.y); acc.z = leaky(acc.z); acc.w = leaky(acc.w);
    *reinterpret_cast<float4*>(&Out[(long)p * 128 + o0]) = acc;
}

__global__ __launch_bounds__(256) void dw4_kernel(const float* In, const void* dwp, const void* dbp,
                                                  float* Out, const int* flag) {
    if (*flag) dw4_body<float>(In, (const float*)dwp, (const float*)dbp, Out);
    else dw4_body<bf16>(In, (const bf16*)dwp, (const bf16*)dbp, Out);
}

// ---------------- avg-pool of 4 consecutive rows (Shat @ H), float4 ----------------
__global__ __launch_bounds__(256) void pool4_kernel(const float* __restrict__ In, float* __restrict__ Out, int F) {
    int tid = blockIdx.x * 256 + threadIdx.x;   // Nout * F/4
    int Fq = F >> 2;
    int j = tid / Fq;
    int f4 = (tid - j * Fq) << 2;
    const float* base = In + (long)(4 * j) * F + f4;
    float4 a = *reinterpret_cast<const float4*>(base);
    float4 b = *reinterpret_cast<const float4*>(base + F);
    float4 c = *reinterpret_cast<const float4*>(base + 2 * F);
    float4 d = *reinterpret_cast<const float4*>(base + 3 * F);
    float4 r;
    r.x = 0.25f * (a.x + b.x + c.x + d.x);
    r.y = 0.25f * (a.y + b.y + c.y + d.y);
    r.z = 0.25f * (a.z + b.z + c.z + d.z);
    r.w = 0.25f * (a.w + b.w + c.w + d.w);
    *reinterpret_cast<float4*>(Out + (long)j * F + f4) = r;
}

// ---------------- GCN attention: 4 rows per block (1 row per wave) ----------------
__global__ __launch_bounds__(256) void attn_kernel(const float* __restrict__ th, const float* __restrict__ outm,
                                                   const int* __restrict__ nbr, float* __restrict__ dst, int co) {
    int n = blockIdx.x * 4 + (threadIdx.x >> 6);
    int l = threadIdx.x & 63;
    float r0 = th[(long)n * 128 + l];
    float r1 = th[(long)n * 128 + 64 + l];
    int mk[KNB];
    float av[KNB];
#pragma unroll
    for (int k = 0; k < KNB; k++) {
        int m = nbr[n * KNB + k];
        mk[k] = m;
        float v = r0 * th[(long)m * 128 + l] + r1 * th[(long)m * 128 + 64 + l];
#pragma unroll
        for (int off = 32; off > 0; off >>= 1) v += __shfl_xor(v, off, 64);
        av[k] = 1.f / (1.f + expf(-v));
    }
    float amax = av[0];
#pragma unroll
    for (int k = 1; k < KNB; k++) amax = fmaxf(amax, av[k]);
    float den = 0.f;
#pragma unroll
    for (int k = 0; k < KNB; k++) { av[k] = expf(av[k] - amax); den += av[k]; }
    float rden = 1.f / den;
    if (l < co) {
        float acc = 0.f;
#pragma unroll
        for (int k = 0; k < KNB; k++) acc += av[k] * outm[(long)mk[k] * co + l];
        dst[(long)n * co + l] = leaky(acc * rden);
    }
}

// ---------------- concats (float4) ----------------
__global__ __launch_bounds__(256) void concat_hcat_kernel(const float* __restrict__ Hd, const float* __restrict__ enc1,
                                                          float* __restrict__ Hcat) {
    int tid = blockIdx.x * 256 + threadIdx.x; // 4096 * 24 quads
    int n = tid / 24;
    int f4 = (tid - n * 24) << 2;
    float4 v;
    if (f4 < 32) v = *reinterpret_cast<const float4*>(&Hd[(long)(n >> 2) * 32 + f4]);
    else v = *reinterpret_cast<const float4*>(&enc1[(long)n * 64 + (f4 - 32)]);
    *reinterpret_cast<float4*>(&Hcat[(long)n * 96 + f4]) = v;
}

__global__ __launch_bounds__(256) void concat_g_kernel(const float* __restrict__ Hdec, const float* __restrict__ H0,
                                                       float* __restrict__ G) {
    int tid = blockIdx.x * 256 + threadIdx.x; // 16384 * 48 quads
    int p = tid / 48;
    int f4 = (tid - p * 48) << 2;
    float4 v;
    if (f4 < 64) v = *reinterpret_cast<const float4*>(&Hdec[(long)(p >> 2) * 64 + f4]);
    else v = *reinterpret_cast<const float4*>(&H0[(long)p * 128 + (f4 - 64)]);
    *reinterpret_cast<float4*>(&G[(long)p * 192 + f4]) = v;
}

// ---------------- classifier: weights in LDS, float4 feature loads ----------------
template <typename TW>
__device__ __forceinline__ void cls_body(const float* __restrict__ F, const TW* __restrict__ wsw,
                                         const TW* __restrict__ wb, TW* __restrict__ out) {
    __shared__ float wl[128 * 16];
    int t = threadIdx.x;
    for (int e = t; e < 2048; e += 256) wl[e] = ldf(wsw, (long)e);
    __syncthreads();
    int tid = blockIdx.x * 256 + t; // 16384*16
    int p = tid >> 4;
    int j = tid & 15;
    float acc = ldf(wb, (long)j);
    const float* fp = F + (long)p * 128;
#pragma unroll 8
    for (int c = 0; c < 128; c += 4) {
        float4 fv = *reinterpret_cast<const float4*>(fp + c);
        acc += fv.x * wl[c * 16 + j] + fv.y * wl[(c + 1) * 16 + j]
             + fv.z * wl[(c + 2) * 16 + j] + fv.w * wl[(c + 3) * 16 + j];
    }
    float m = acc;
#pragma unroll
    for (int s = 8; s > 0; s >>= 1) m = fmaxf(m, __shfl_xor(m, s, 16));
    float e = expf(acc - m);
    float d = e;
#pragma unroll
    for (int s = 8; s > 0; s >>= 1) d += __shfl_xor(d, s, 16);
    float r = e / d;
    if constexpr (sizeof(TW) == 2) out[tid] = __float2bfloat16(r);
    else out[tid] = r;
}

__global__ __launch_bounds__(256) void cls_kernel(const float* F, const void* wsw, const void* wb,
                                                  void* out, const int* flag) {
    if (*flag) cls_body<float>(F, (const float*)wsw, (const float*)wb, (float*)out);
    else cls_body<bf16>(F, (const bf16*)wsw, (const bf16*)wb, (bf16*)out);
}

// ================= host side =================
extern "C" void kernel_launch(void* const* d_in, const int* in_sizes, int n_in,
                              void* d_out, int out_size, void* d_ws, size_t ws_size,
                              hipStream_t stream) {
    bool dict = (in_sizes[1] > 1000000);
    int I_x, I_nbr_a, I_nbr_b, I_hg, I_ws, I_e0, I_e1, I_d0, I_tg;
    if (dict) {
        I_x = 0; I_nbr_a = 5; I_nbr_b = 6; I_hg = 7; I_e0 = 13; I_e1 = 19; I_d0 = 25; I_tg = 31; I_ws = 37;
    } else {
        I_x = 0; I_hg = 1; I_e0 = 7; I_e1 = 13; I_d0 = 19; I_tg = 25; I_ws = 31; I_nbr_a = 37; I_nbr_b = 38;
    }
    const void* x    = d_in[I_x];
    const int* nbr_a = (const int*)d_in[I_nbr_a];
    const int* nbr_b = (const int*)d_in[I_nbr_b];
    const void* hg   = d_in[I_hg + 0];
    const void* hb   = d_in[I_hg + 1];
    const void* hpw  = d_in[I_hg + 2];
    const void* hpb  = d_in[I_hg + 3];
    const void* hdw  = d_in[I_hg + 4];
    const void* hdb  = d_in[I_hg + 5];
    const void* e0_g = d_in[I_e0 + 0];
    const void* e0_b = d_in[I_e0 + 1];
    const void* e0_wt= d_in[I_e0 + 2];
    const void* e0_bt= d_in[I_e0 + 3];
    const void* e0_wo= d_in[I_e0 + 4];
    const void* e0_bo= d_in[I_e0 + 5];
    const void* e1_g = d_in[I_e1 + 0];
    const void* e1_b = d_in[I_e1 + 1];
    const void* e1_wt= d_in[I_e1 + 2];
    const void* e1_bt= d_in[I_e1 + 3];
    const void* e1_wo= d_in[I_e1 + 4];
    const void* e1_bo= d_in[I_e1 + 5];
    const void* d0_g = d_in[I_d0 + 0];
    const void* d0_b = d_in[I_d0 + 1];
    const void* d0_wt= d_in[I_d0 + 2];
    const void* d0_bt= d_in[I_d0 + 3];
    const void* d0_wo= d_in[I_d0 + 4];
    const void* d0_bo= d_in[I_d0 + 5];
    const void* tg   = d_in[I_tg + 0];
    const void* tb   = d_in[I_tg + 1];
    const void* tpw  = d_in[I_tg + 2];
    const void* tpb  = d_in[I_tg + 3];
    const void* tdw  = d_in[I_tg + 4];
    const void* tdb  = d_in[I_tg + 5];
    const void* wsw  = d_in[I_ws + 0];
    const void* wb   = d_in[I_ws + 1];

    float* W = (float*)d_ws;
    float* AB_a  = W + 0;
    float* AB_b  = W + 256;
    float* WF1   = W + 512;       // up to 200*128
    float* BF1   = W + 33280;
    float* WF2   = W + 33536;     // up to 128*64
    float* BF2   = W + 41728;
    int*   dflag = (int*)(W + 49152);
    float* PART  = W + 49408;     // 2 * 256ch * 256blk = 131072 floats
    float* R0    = W + 196608;         // 16384*192
    float* R1    = R0 + (long)N0*192;  // 16384*128
    float* H1b   = R1 + (long)N0*128;  // 4096*128
    float* THb   = H1b + (long)N1*128; // 4096*128
    float* OUTb  = THb + (long)N1*128; // 4096*64
    float* ENC1  = OUTb + (long)N1*64; // 4096*64
    float* H2b   = ENC1 + (long)N1*64; // 1024*64
    float* HDb   = H2b + (long)N2*64;  // 1024*32
    float* HCAT  = HDb + (long)N2*32;  // 4096*96
    float* HDEC  = HCAT + (long)N1*96; // 4096*64

    detect_kernel<<<1, 64, 0, stream>>>((const unsigned short*)x, dflag);

    // ---- head SSConv ----
    bnA_kernel<<<256, 256, 0, stream>>>(x, N0, C_IN, PART, dflag, 1);
    bnB_kernel<<<C_IN, 256, 0, stream>>>(PART, N0, hg, hb, AB_a, AB_b, dflag);
    fold_kernel<<<128, 256, 0, stream>>>(hpw, hpb, AB_a, AB_b, WF1, BF1, C_IN, 128, 1, dflag);
    gemm4_dyn_kernel<<<(N0 * 128 / 4) / 256, 256, 0, stream>>>(x, WF1, BF1, R0, C_IN, 128, dflag);
    dw4_kernel<<<(N0 * 32) / 256, 256, 0, stream>>>(R0, hdw, hdb, R1, dflag); // R1 = enc0
    pool4_kernel<<<(N1 * 32) / 256, 256, 0, stream>>>(R1, H1b, 128);

    // ---- GCN e0: 128 -> 64 ----
    bnA_kernel<<<256, 256, 0, stream>>>(H1b, N1, 128, PART, dflag, 0);
    bnB_kernel<<<128, 256, 0, stream>>>(PART, N1, e0_g, e0_b, AB_a, AB_b, dflag);
    fold2_kernel<<<192, 256, 0, stream>>>(e0_wt, e0_bt, e0_wo, e0_bo, AB_a, AB_b,
                                          WF1, BF1, WF2, BF2, 128, 128, 64, dflag);
    {
        int nb1 = (N1 * 32) / 256, nb2 = (N1 * 16) / 256; // th (Co=128), out (Co=64)
        gemm2_f32_kernel<0><<<nb1 + nb2, 256, 0, stream>>>(H1b, WF1, BF1, THb, 128,
                                                           WF2, BF2, OUTb, 64, 128, nb1);
    }
    attn_kernel<<<N1 / 4, 256, 0, stream>>>(THb, OUTb, nbr_a, ENC1, 64);
    pool4_kernel<<<(N2 * 16) / 256, 256, 0, stream>>>(ENC1, H2b, 64);

    // ---- GCN e1: 64 -> 32 ----
    bnA_kernel<<<256, 256, 0, stream>>>(H2b, N2, 64, PART, dflag, 0);
    bnB_kernel<<<64, 256, 0, stream>>>(PART, N2, e1_g, e1_b, AB_a, AB_b, dflag);
    fold2_kernel<<<160, 256, 0, stream>>>(e1_wt, e1_bt, e1_wo, e1_bo, AB_a, AB_b,
                                          WF1, BF1, WF2, BF2, 64, 128, 32, dflag);
    {
        int nb1 = (N2 * 32) / 256, nb2 = (N2 * 8) / 256;
        gemm2_f32_kernel<0><<<nb1 + nb2, 256, 0, stream>>>(H2b, WF1, BF1, THb, 128,
                                                           WF2, BF2, OUTb, 32, 64, nb1);
    }
    attn_kernel<<<N2 / 4, 256, 0, stream>>>(THb, OUTb, nbr_b, HDb, 32);

    // ---- decoder GCN d0 ----
    concat_hcat_kernel<<<(N1 * 24) / 256, 256, 0, stream>>>(HDb, ENC1, HCAT);
    bnA_kernel<<<256, 256, 0, stream>>>(HCAT, N1, 96, PART, dflag, 0);
    bnB_kernel<<<96, 256, 0, stream>>>(PART, N1, d0_g, d0_b, AB_a, AB_b, dflag);
    fold2_kernel<<<192, 256, 0, stream>>>(d0_wt, d0_bt, d0_wo, d0_bo, AB_a, AB_b,
                                          WF1, BF1, WF2, BF2, 96, 128, 64, dflag);
    {
        int nb1 = (N1 * 32) / 256, nb2 = (N1 * 16) / 256;
        gemm2_f32_kernel<0><<<nb1 + nb2, 256, 0, stream>>>(HCAT, WF1, BF1, THb, 128,
                                                           WF2, BF2, OUTb, 64, 96, nb1);
    }
    attn_kernel<<<N1 / 4, 256, 0, stream>>>(THb, OUTb, nbr_a, HDEC, 64);

    // ---- tail ----
    concat_g_kernel<<<(N0 * 48) / 256, 256, 0, stream>>>(HDEC, R1, R0); // R0 = G
    bnA_kernel<<<256, 256, 0, stream>>>(R0, N0, 192, PART, dflag, 0);
    bnB_kernel<<<192, 256, 0, stream>>>(PART, N0, tg, tb, AB_a, AB_b, dflag);
    fold_kernel<<<128, 256, 0, stream>>>(tpw, tpb, AB_a, AB_b, WF1, BF1, 192, 128, 1, dflag);
    gemm4_f32_kernel<1><<<(N0 * 128 / 4) / 256, 256, 0, stream>>>(R0, WF1, BF1, R1, 192, 128); // R1 = T1
    dw4_kernel<<<(N0 * 32) / 256, 256, 0, stream>>>(R1, tdw, tdb, R0, dflag); // R0 = F
    cls_kernel<<<(N0 * NCLS) / 256, 256, 0, stream>>>(R0, wsw, wb, d_out, dflag);
}